// Round 3
// baseline (1297.933 us; speedup 1.0000x reference)
//
#include <hip/hip_runtime.h>
#include <math.h>

// Problem constants
constexpr int L  = 4096;      // seq len
constexpr int D  = 1024;      // d_model
constexpr int N  = 16;        // hiddens per channel
constexpr int NC = 64;        // chunks
constexpr int T  = L / NC;    // 64 steps per chunk
constexpr int G  = 16;        // d-groups per chunk
constexpr int DG = D / G;     // 64 channels per block
constexpr int NB = NC * G;    // 1024 blocks
constexpr int SPB = DG * N;   // states per block = 1024 (float2 each)

__device__ __forceinline__ float softplus_f(float v) {
    return fmaxf(v, 0.0f) + log1pf(expf(-fabsf(v)));
}

// One fused kernel: per-block local scan + decoupled look-back + output.
// Ticket virtualization makes the look-back deadlock-free regardless of HW
// dispatch order: virtual id = atomicAdd order, so all predecessors of a
// running block already started, and publishing a local state requires no
// waiting.
__global__ __launch_bounds__(256, 4) void k_fused(
    const float* __restrict__ x, const float* __restrict__ Delta,
    const float* __restrict__ A_re, const float* __restrict__ A_im,
    const float* __restrict__ B_re, const float* __restrict__ B_im,
    const float* __restrict__ C_re, const float* __restrict__ C_im,
    const float* __restrict__ Dp, float* __restrict__ out,
    float4* __restrict__ pay, int* __restrict__ flags, int* __restrict__ ticket)
{
    __shared__ float xs[T * DG];     // 16 KiB x slice
    __shared__ int s_tkt;
    const int tid = threadIdx.x;
    if (tid == 0) s_tkt = atomicAdd(ticket, 1);
    __syncthreads();
    const int vb = s_tkt;
    const int c  = vb / G;           // chunk index
    const int dg = vb - c * G;       // d-group index

    // ---- stage x[cT..cT+T) x [dg*DG .. +DG) into LDS, coalesced float4 ----
    {
        const float* xg = x + (size_t)(c * T) * D + dg * DG;
        #pragma unroll
        for (int it = 0; it < 4; ++it) {
            int row  = it * 16 + (tid >> 4);
            int col4 = (tid & 15) * 4;
            float4 v = *(const float4*)(xg + (size_t)row * D + col4);
            *(float4*)&xs[row * DG + col4] = v;
        }
    }

    // ---- per-state constants: thread owns d_local = tid>>2, n = (tid&3)*4+j
    const int dl = tid >> 2;
    const int q  = tid & 3;
    const int d  = dg * DG + dl;
    const float dt  = softplus_f(Delta[d]);
    const float dpv = Dp[d];
    const int pidx  = d * N + q * 4;

    float4 ar4 = *(const float4*)(A_re + pidx);
    float4 ai4 = *(const float4*)(A_im + pidx);
    float4 br4 = *(const float4*)(B_re + pidx);
    float4 bi4 = *(const float4*)(B_im + pidx);
    float4 c_r4 = *(const float4*)(C_re + pidx);
    float4 c_i4 = *(const float4*)(C_im + pidx);

    float Lr[4], Li[4], Tr[4], Ti[4], Cr[4], Ci[4];
    {
        const float arr[4] = {ar4.x, ar4.y, ar4.z, ar4.w};
        const float aii[4] = {ai4.x, ai4.y, ai4.z, ai4.w};
        const float brr[4] = {br4.x, br4.y, br4.z, br4.w};
        const float bii[4] = {bi4.x, bi4.y, bi4.z, bi4.w};
        const float crr[4] = {c_r4.x, c_r4.y, c_r4.z, c_r4.w};
        const float cii[4] = {c_i4.x, c_i4.y, c_i4.z, c_i4.w};
        #pragma unroll
        for (int j = 0; j < 4; ++j) {
            float e  = expf(arr[j] * dt);
            float th = aii[j] * dt;
            Lr[j] = e * cosf(th);
            Li[j] = e * sinf(th);
            // Lambda^T via 6 squarings (T = 64)
            float tr = Lr[j], ti = Li[j];
            #pragma unroll
            for (int k = 0; k < 6; ++k) {
                float nr = tr * tr - ti * ti;
                ti = 2.0f * tr * ti;
                tr = nr;
            }
            Tr[j] = tr; Ti[j] = ti;
            // C' = dt * (C*B) so that out = Re(sum_n C'. g), g = Lam g + x
            Cr[j] = dt * (crr[j] * brr[j] - cii[j] * bii[j]);
            Ci[j] = dt * (crr[j] * bii[j] + cii[j] * brr[j]);
        }
    }

    __syncthreads();   // xs ready

    // ---- phase 2: local scan, zero init ----
    float gr[4] = {0, 0, 0, 0}, gi[4] = {0, 0, 0, 0};
    #pragma unroll 4
    for (int i = 0; i < T; ++i) {
        float xv = xs[i * DG + dl];
        #pragma unroll
        for (int j = 0; j < 4; ++j) {
            float t2 = fmaf(-Li[j], gi[j], xv);
            float nr = fmaf(Lr[j], gr[j], t2);
            gi[j] = fmaf(Lr[j], gi[j], Li[j] * gr[j]);
            gr[j] = nr;
        }
    }

    // ---- publish local end-state, then flag (agent scope, release) ----
    {
        float4* dst = pay + ((size_t)vb * SPB + dl * N + q * 4) / 2;
        dst[0] = make_float4(gr[0], gi[0], gr[1], gi[1]);
        dst[1] = make_float4(gr[2], gi[2], gr[3], gi[3]);
    }
    __threadfence();
    __syncthreads();
    if (tid == 0)
        __hip_atomic_store(&flags[vb], 1, __ATOMIC_RELEASE, __HIP_MEMORY_SCOPE_AGENT);

    // ---- phase 3: fold predecessors p = 0..c-1 ascending:
    //      carry = Lam^T * carry + s_p   (batched 4-wide loads) ----
    float kr[4] = {0, 0, 0, 0}, ki[4] = {0, 0, 0, 0};
    int p = 0;
    for (; p + 4 <= c; p += 4) {
        #pragma unroll
        for (int u = 0; u < 4; ++u)
            while (__hip_atomic_load(&flags[(p + u) * G + dg], __ATOMIC_ACQUIRE,
                                     __HIP_MEMORY_SCOPE_AGENT) == 0)
                __builtin_amdgcn_s_sleep(1);
        float4 a0[4], a1[4];
        #pragma unroll
        for (int u = 0; u < 4; ++u) {
            const float4* src =
                pay + ((size_t)((p + u) * G + dg) * SPB + dl * N + q * 4) / 2;
            a0[u] = src[0];
            a1[u] = src[1];
        }
        #pragma unroll
        for (int u = 0; u < 4; ++u) {
            const float sx[4] = {a0[u].x, a0[u].z, a1[u].x, a1[u].z};
            const float sy[4] = {a0[u].y, a0[u].w, a1[u].y, a1[u].w};
            #pragma unroll
            for (int j = 0; j < 4; ++j) {
                float nr = fmaf(Tr[j], kr[j], fmaf(-Ti[j], ki[j], sx[j]));
                ki[j] = fmaf(Tr[j], ki[j], fmaf(Ti[j], kr[j], sy[j]));
                kr[j] = nr;
            }
        }
    }
    for (; p < c; ++p) {
        while (__hip_atomic_load(&flags[p * G + dg], __ATOMIC_ACQUIRE,
                                 __HIP_MEMORY_SCOPE_AGENT) == 0)
            __builtin_amdgcn_s_sleep(1);
        const float4* src = pay + ((size_t)(p * G + dg) * SPB + dl * N + q * 4) / 2;
        float4 a0 = src[0], a1 = src[1];
        const float sx[4] = {a0.x, a0.z, a1.x, a1.z};
        const float sy[4] = {a0.y, a0.w, a1.y, a1.w};
        #pragma unroll
        for (int j = 0; j < 4; ++j) {
            float nr = fmaf(Tr[j], kr[j], fmaf(-Ti[j], ki[j], sx[j]));
            ki[j] = fmaf(Tr[j], ki[j], fmaf(Ti[j], kr[j], sy[j]));
            kr[j] = nr;
        }
    }

    // ---- phase 4: re-run scan from resolved carry, contract, store ----
    #pragma unroll
    for (int j = 0; j < 4; ++j) { gr[j] = kr[j]; gi[j] = ki[j]; }
    const size_t obase = (size_t)(c * T) * D + d;
    #pragma unroll 2
    for (int i = 0; i < T; ++i) {
        float xv = xs[i * DG + dl];
        float acc = 0.0f;
        #pragma unroll
        for (int j = 0; j < 4; ++j) {
            float t2 = fmaf(-Li[j], gi[j], xv);
            float nr = fmaf(Lr[j], gr[j], t2);
            gi[j] = fmaf(Lr[j], gi[j], Li[j] * gr[j]);
            gr[j] = nr;
            acc = fmaf(Cr[j], gr[j], acc);
            acc = fmaf(-Ci[j], gi[j], acc);
        }
        acc += __shfl_xor(acc, 1);
        acc += __shfl_xor(acc, 2);
        if (q == 0) out[obase + (size_t)i * D] = fmaf(dpv, xv, acc);
    }
}

extern "C" void kernel_launch(void* const* d_in, const int* in_sizes, int n_in,
                              void* d_out, int out_size, void* d_ws, size_t ws_size,
                              hipStream_t stream) {
    const float* x     = (const float*)d_in[0];
    const float* Delta = (const float*)d_in[1];
    const float* A_re  = (const float*)d_in[2];
    const float* A_im  = (const float*)d_in[3];
    const float* B_re  = (const float*)d_in[4];
    const float* B_im  = (const float*)d_in[5];
    const float* C_re  = (const float*)d_in[6];
    const float* C_im  = (const float*)d_in[7];
    const float* Dp    = (const float*)d_in[8];
    float* out = (float*)d_out;

    // ws layout: [payload NB*SPB float2 = 8 MiB][flags NB int][ticket int]
    float4* pay = (float4*)d_ws;
    size_t paybytes = (size_t)NB * SPB * sizeof(float2);
    int* flags  = (int*)((char*)d_ws + paybytes);
    // flags + ticket must be zeroed every call (ws is re-poisoned to 0xAA)
    hipMemsetAsync(flags, 0, (NB + 1) * sizeof(int), stream);
    int* ticket = flags + NB;

    k_fused<<<NB, 256, 0, stream>>>(x, Delta, A_re, A_im, B_re, B_im,
                                    C_re, C_im, Dp, out, pay, flags, ticket);
}

// Round 4
// 143.555 us; speedup vs baseline: 9.0414x; 9.0414x over previous
//
#include <hip/hip_runtime.h>
#include <math.h>

// Problem constants
constexpr int L  = 4096;    // seq len
constexpr int D  = 1024;    // d_model
constexpr int N  = 16;      // hiddens per channel
constexpr int NC = 128;     // chunks
constexpr int T  = L / NC;  // 32 steps per chunk

__device__ __forceinline__ float softplus_f(float v) {
    return fmaxf(v, 0.0f) + log1pf(expf(-fabsf(v)));
}

// Compute per-(d,n) Lambda for 4 consecutive n from float4 A loads.
__device__ __forceinline__ void lam4(float4 a, float4 b, float dt,
                                     float* Lr, float* Li) {
    const float ar[4] = {a.x, a.y, a.z, a.w};
    const float ai[4] = {b.x, b.y, b.z, b.w};
    #pragma unroll
    for (int k = 0; k < 4; ++k) {
        float e  = expf(ar[k] * dt);
        float th = ai[k] * dt;
        Lr[k] = e * cosf(th);
        Li[k] = e * sinf(th);
    }
}

// K1: thread = (c, d), owns all 16 states. Local scan g = Lam*g + x, zero init.
// End states stored as float4 [c][j][d], j = n/2 packing (gr,gi) for n=2j,2j+1.
__global__ __launch_bounds__(256) void k_local(
    const float* __restrict__ x,
    const float* __restrict__ Delta,
    const float* __restrict__ A_re,
    const float* __restrict__ A_im,
    float4* __restrict__ s4)
{
    const int tid = blockIdx.x * 256 + threadIdx.x;  // c*D + d
    const int d = tid & (D - 1);
    const int c = tid >> 10;

    const float dt = softplus_f(Delta[d]);
    float Lr[16], Li[16];
    {
        const float4* ar4 = (const float4*)(A_re + d * N);
        const float4* ai4 = (const float4*)(A_im + d * N);
        #pragma unroll
        for (int j4 = 0; j4 < 4; ++j4)
            lam4(ar4[j4], ai4[j4], dt, Lr + 4 * j4, Li + 4 * j4);
    }

    float gr[16], gi[16];
    #pragma unroll
    for (int n = 0; n < 16; ++n) { gr[n] = 0.0f; gi[n] = 0.0f; }

    const float* xp = x + (size_t)c * T * D + d;
    for (int i0 = 0; i0 < T; i0 += 8) {
        float xv[8];
        #pragma unroll
        for (int u = 0; u < 8; ++u) xv[u] = xp[(size_t)(i0 + u) * D];
        #pragma unroll
        for (int u = 0; u < 8; ++u) {
            #pragma unroll
            for (int n = 0; n < 16; ++n) {
                float t2 = fmaf(-Li[n], gi[n], xv[u]);
                float nr = fmaf(Lr[n], gr[n], t2);
                gi[n] = fmaf(Lr[n], gi[n], Li[n] * gr[n]);
                gr[n] = nr;
            }
        }
    }
    #pragma unroll
    for (int j = 0; j < 8; ++j)
        s4[(size_t)(c * 8 + j) * D + d] =
            make_float4(gr[2 * j], gi[2 * j], gr[2 * j + 1], gi[2 * j + 1]);
}

// K2: thread = (n, d), serial scan over NC chunk states (in-place -> carries).
__global__ __launch_bounds__(256) void k_scan(
    const float* __restrict__ Delta,
    const float* __restrict__ A_re,
    const float* __restrict__ A_im,
    float2* __restrict__ s2)
{
    const int tid = blockIdx.x * 256 + threadIdx.x;  // n*D + d
    const int d = tid & (D - 1);
    const int n = tid >> 10;

    const float dt = softplus_f(Delta[d]);
    float ar = A_re[d * N + n] * dt;
    float ai = A_im[d * N + n] * dt;
    float e  = expf(ar);
    float Lr = e * cosf(ai), Li = e * sinf(ai);
    // Lam^T via 5 squarings (T = 32)
    #pragma unroll
    for (int k = 0; k < 5; ++k) {
        float nr = Lr * Lr - Li * Li;
        Li = 2.0f * Lr * Li;
        Lr = nr;
    }

    const int j = n >> 1, h = n & 1;
    float cr = 0.0f, ci = 0.0f;
    for (int c0 = 0; c0 < NC; c0 += 8) {
        float2 sv[8];
        #pragma unroll
        for (int u = 0; u < 8; ++u)
            sv[u] = s2[((size_t)((c0 + u) * 8 + j) * D + d) * 2 + h];
        #pragma unroll
        for (int u = 0; u < 8; ++u) {
            s2[((size_t)((c0 + u) * 8 + j) * D + d) * 2 + h] = make_float2(cr, ci);
            float nr = fmaf(Lr, cr, fmaf(-Li, ci, sv[u].x));
            ci = fmaf(Lr, ci, fmaf(Li, cr, sv[u].y));
            cr = nr;
        }
    }
}

// K3: thread = (c, d), owns all 16 states. Re-run scan from carry, contract
// with C' = dt*C*B over n in-register, add D*x, coalesced store.
__global__ __launch_bounds__(256) void k_out(
    const float* __restrict__ x,
    const float* __restrict__ Delta,
    const float* __restrict__ A_re,
    const float* __restrict__ A_im,
    const float* __restrict__ B_re,
    const float* __restrict__ B_im,
    const float* __restrict__ C_re,
    const float* __restrict__ C_im,
    const float* __restrict__ Dp,
    const float4* __restrict__ s4,
    float* __restrict__ out)
{
    const int tid = blockIdx.x * 256 + threadIdx.x;  // c*D + d
    const int d = tid & (D - 1);
    const int c = tid >> 10;

    const float dt  = softplus_f(Delta[d]);
    const float dpv = Dp[d];

    float Lr[16], Li[16], Cr[16], Ci[16];
    {
        const float4* ar4 = (const float4*)(A_re + d * N);
        const float4* ai4 = (const float4*)(A_im + d * N);
        const float4* br4 = (const float4*)(B_re + d * N);
        const float4* bi4 = (const float4*)(B_im + d * N);
        const float4* cr4 = (const float4*)(C_re + d * N);
        const float4* ci4 = (const float4*)(C_im + d * N);
        #pragma unroll
        for (int j4 = 0; j4 < 4; ++j4) {
            lam4(ar4[j4], ai4[j4], dt, Lr + 4 * j4, Li + 4 * j4);
            float4 b0 = br4[j4], b1 = bi4[j4], c0 = cr4[j4], c1 = ci4[j4];
            const float brr[4] = {b0.x, b0.y, b0.z, b0.w};
            const float bii[4] = {b1.x, b1.y, b1.z, b1.w};
            const float crr[4] = {c0.x, c0.y, c0.z, c0.w};
            const float cii[4] = {c1.x, c1.y, c1.z, c1.w};
            #pragma unroll
            for (int k = 0; k < 4; ++k) {
                Cr[4 * j4 + k] = dt * (crr[k] * brr[k] - cii[k] * bii[k]);
                Ci[4 * j4 + k] = dt * (crr[k] * bii[k] + cii[k] * brr[k]);
            }
        }
    }

    float gr[16], gi[16];
    #pragma unroll
    for (int j = 0; j < 8; ++j) {
        float4 cv = s4[(size_t)(c * 8 + j) * D + d];
        gr[2 * j]     = cv.x; gi[2 * j]     = cv.y;
        gr[2 * j + 1] = cv.z; gi[2 * j + 1] = cv.w;
    }

    const float* xp = x   + (size_t)c * T * D + d;
    float*       op = out + (size_t)c * T * D + d;
    for (int i0 = 0; i0 < T; i0 += 8) {
        float xv[8];
        #pragma unroll
        for (int u = 0; u < 8; ++u) xv[u] = xp[(size_t)(i0 + u) * D];
        #pragma unroll
        for (int u = 0; u < 8; ++u) {
            float acc = dpv * xv[u];
            #pragma unroll
            for (int n = 0; n < 16; ++n) {
                float t2 = fmaf(-Li[n], gi[n], xv[u]);
                float nr = fmaf(Lr[n], gr[n], t2);
                gi[n] = fmaf(Lr[n], gi[n], Li[n] * gr[n]);
                gr[n] = nr;
                acc = fmaf(Cr[n], gr[n], acc);
                acc = fmaf(-Ci[n], gi[n], acc);
            }
            op[(size_t)(i0 + u) * D] = acc;
        }
    }
}

extern "C" void kernel_launch(void* const* d_in, const int* in_sizes, int n_in,
                              void* d_out, int out_size, void* d_ws, size_t ws_size,
                              hipStream_t stream) {
    const float* x     = (const float*)d_in[0];
    const float* Delta = (const float*)d_in[1];
    const float* A_re  = (const float*)d_in[2];
    const float* A_im  = (const float*)d_in[3];
    const float* B_re  = (const float*)d_in[4];
    const float* B_im  = (const float*)d_in[5];
    const float* C_re  = (const float*)d_in[6];
    const float* C_im  = (const float*)d_in[7];
    const float* Dp    = (const float*)d_in[8];
    float* out = (float*)d_out;

    float4* s4 = (float4*)d_ws;   // NC * 8 * D float4 = 16 MiB
    float2* s2 = (float2*)d_ws;

    k_local<<<(NC * D) / 256, 256, 0, stream>>>(x, Delta, A_re, A_im, s4);
    k_scan<<<(N * D) / 256, 256, 0, stream>>>(Delta, A_re, A_im, s2);
    k_out<<<(NC * D) / 256, 256, 0, stream>>>(x, Delta, A_re, A_im,
                                              B_re, B_im, C_re, C_im, Dp,
                                              s4, out);
}

// Round 5
// 117.489 us; speedup vs baseline: 11.0473x; 1.2219x over previous
//
#include <hip/hip_runtime.h>
#include <math.h>

// Problem constants
constexpr int L  = 4096;    // seq len
constexpr int D  = 1024;    // d_model
constexpr int N  = 16;      // hiddens per channel
constexpr int NC = 128;     // chunks
constexpr int T  = L / NC;  // 32 steps per chunk

__device__ __forceinline__ float softplus_f(float v) {
    return fmaxf(v, 0.0f) + log1pf(expf(-fabsf(v)));
}

// K0: per (n,d) parameter precompute -> [n][d] arrays (coalesced for hot kernels).
//   Lam = exp(dt*A), LamT = Lam^T (5 squarings), C' = dt*(C*B)
__global__ __launch_bounds__(256) void k_pre(
    const float* __restrict__ Delta,
    const float* __restrict__ A_re, const float* __restrict__ A_im,
    const float* __restrict__ B_re, const float* __restrict__ B_im,
    const float* __restrict__ C_re, const float* __restrict__ C_im,
    float* __restrict__ PLr, float* __restrict__ PLi,
    float* __restrict__ PTr, float* __restrict__ PTi,
    float* __restrict__ PCr, float* __restrict__ PCi)
{
    const int tid = blockIdx.x * 256 + threadIdx.x;  // n*D + d
    const int d = tid & (D - 1);
    const int n = tid >> 10;
    const int idx = d * N + n;

    const float dt = softplus_f(Delta[d]);
    float e  = expf(A_re[idx] * dt);
    float th = A_im[idx] * dt;
    float lr = e * cosf(th), li = e * sinf(th);
    float tr = lr, ti = li;
    #pragma unroll
    for (int k = 0; k < 5; ++k) {   // Lam^32
        float nr = tr * tr - ti * ti;
        ti = 2.0f * tr * ti;
        tr = nr;
    }
    float br = B_re[idx], bi = B_im[idx];
    float cr = C_re[idx], ci = C_im[idx];
    PLr[tid] = lr; PLi[tid] = li;
    PTr[tid] = tr; PTi[tid] = ti;
    PCr[tid] = dt * (cr * br - ci * bi);
    PCi[tid] = dt * (cr * bi + ci * br);
}

// K1: thread = (c, d, q): 4 states (n = q*4..q*4+3). Local scan, zero init.
// x staged via LDS. End states -> s2[c][n][d] (coalesced).
__global__ __launch_bounds__(256, 4) void k_local(
    const float* __restrict__ x,
    const float* __restrict__ PLr, const float* __restrict__ PLi,
    float2* __restrict__ s2)
{
    __shared__ float xs[T * 64];          // 8 KiB
    const int bc = blockIdx.x >> 4;       // chunk
    const int dg = blockIdx.x & 15;       // 64-wide d group
    const int tid = threadIdx.x;

    const float* xg = x + (size_t)bc * T * D + dg * 64;
    #pragma unroll
    for (int it = 0; it < 2; ++it) {      // 2048 floats, float4-coalesced
        int f = tid * 4 + it * 1024;
        int row = f >> 6, col = f & 63;
        *(float4*)&xs[row * 64 + col] = *(const float4*)(xg + (size_t)row * D + col);
    }

    const int q = tid & 3, dl = tid >> 2;
    const int d = dg * 64 + dl;
    float Lr[4], Li[4];
    #pragma unroll
    for (int j = 0; j < 4; ++j) {
        int n = q * 4 + j;
        Lr[j] = PLr[n * D + d];
        Li[j] = PLi[n * D + d];
    }
    __syncthreads();

    float gr[4] = {0, 0, 0, 0}, gi[4] = {0, 0, 0, 0};
    #pragma unroll
    for (int i = 0; i < T; ++i) {
        float xv = xs[i * 64 + dl];
        #pragma unroll
        for (int j = 0; j < 4; ++j) {
            float t2 = fmaf(-Li[j], gi[j], xv);
            float nr = fmaf(Lr[j], gr[j], t2);
            gi[j] = fmaf(Lr[j], gi[j], Li[j] * gr[j]);
            gr[j] = nr;
        }
    }
    #pragma unroll
    for (int j = 0; j < 4; ++j) {
        int n = q * 4 + j;
        s2[((size_t)bc * N + n) * D + d] = make_float2(gr[j], gi[j]);
    }
}

// K2: thread = (n,d): serial scan over NC chunk states, in-place -> carry
// before each chunk. Batch 16 loads.
__global__ __launch_bounds__(256) void k_scan(
    const float* __restrict__ PTr, const float* __restrict__ PTi,
    float2* __restrict__ s2)
{
    const int tid = blockIdx.x * 256 + threadIdx.x;  // n*D + d
    const float Lr = PTr[tid], Li = PTi[tid];

    float cr = 0.0f, ci = 0.0f;
    for (int c0 = 0; c0 < NC; c0 += 16) {
        float2 sv[16];
        #pragma unroll
        for (int u = 0; u < 16; ++u)
            sv[u] = s2[(size_t)(c0 + u) * (N * D) + tid];
        #pragma unroll
        for (int u = 0; u < 16; ++u) {
            s2[(size_t)(c0 + u) * (N * D) + tid] = make_float2(cr, ci);
            float nr = fmaf(Lr, cr, fmaf(-Li, ci, sv[u].x));
            ci = fmaf(Lr, ci, fmaf(Li, cr, sv[u].y));
            cr = nr;
        }
    }
}

// K3: thread = (c, d, q): re-run scan from carry for 4 states, contract with
// C', butterfly-reduce over q, add D*x, full-lane stores (4 rows buffered).
__global__ __launch_bounds__(256, 4) void k_out(
    const float* __restrict__ x,
    const float* __restrict__ PLr, const float* __restrict__ PLi,
    const float* __restrict__ PCr, const float* __restrict__ PCi,
    const float* __restrict__ Dp,
    const float2* __restrict__ s2,
    float* __restrict__ out)
{
    __shared__ float xs[T * 64];
    const int bc = blockIdx.x >> 4;
    const int dg = blockIdx.x & 15;
    const int tid = threadIdx.x;

    const float* xg = x + (size_t)bc * T * D + dg * 64;
    #pragma unroll
    for (int it = 0; it < 2; ++it) {
        int f = tid * 4 + it * 1024;
        int row = f >> 6, col = f & 63;
        *(float4*)&xs[row * 64 + col] = *(const float4*)(xg + (size_t)row * D + col);
    }

    const int q = tid & 3, dl = tid >> 2;
    const int d = dg * 64 + dl;
    float Lr[4], Li[4], Cr[4], Ci[4], gr[4], gi[4];
    #pragma unroll
    for (int j = 0; j < 4; ++j) {
        int n = q * 4 + j;
        Lr[j] = PLr[n * D + d];
        Li[j] = PLi[n * D + d];
        Cr[j] = PCr[n * D + d];
        Ci[j] = PCi[n * D + d];
        float2 cv = s2[((size_t)bc * N + n) * D + d];
        gr[j] = cv.x; gi[j] = cv.y;
    }
    const float dpv = Dp[d];
    float* og = out + (size_t)bc * T * D + dg * 64;
    __syncthreads();

    #pragma unroll
    for (int ib = 0; ib < T / 4; ++ib) {
        float keep = 0.0f;
        #pragma unroll
        for (int u = 0; u < 4; ++u) {
            int i = ib * 4 + u;
            float xv = xs[i * 64 + dl];
            float acc = 0.0f;
            #pragma unroll
            for (int j = 0; j < 4; ++j) {
                float t2 = fmaf(-Li[j], gi[j], xv);
                float nr = fmaf(Lr[j], gr[j], t2);
                gi[j] = fmaf(Lr[j], gi[j], Li[j] * gr[j]);
                gr[j] = nr;
                acc = fmaf(Cr[j], gr[j], acc);
                acc = fmaf(-Ci[j], gi[j], acc);
            }
            acc += __shfl_xor(acc, 1);    // reduce over q-pairs
            acc += __shfl_xor(acc, 2);
            acc = fmaf(dpv, xv, acc);     // every lane has the full sum
            keep = (q == u) ? acc : keep; // lane q keeps iteration u==q
        }
        og[(size_t)(ib * 4 + q) * D + dl] = keep;  // all 64 lanes store
    }
}

extern "C" void kernel_launch(void* const* d_in, const int* in_sizes, int n_in,
                              void* d_out, int out_size, void* d_ws, size_t ws_size,
                              hipStream_t stream) {
    const float* x     = (const float*)d_in[0];
    const float* Delta = (const float*)d_in[1];
    const float* A_re  = (const float*)d_in[2];
    const float* A_im  = (const float*)d_in[3];
    const float* B_re  = (const float*)d_in[4];
    const float* B_im  = (const float*)d_in[5];
    const float* C_re  = (const float*)d_in[6];
    const float* C_im  = (const float*)d_in[7];
    const float* Dp    = (const float*)d_in[8];
    float* out = (float*)d_out;

    // ws: [s2: NC*N*D float2 = 16 MiB][6 param arrays of N*D floats = 384 KiB]
    float2* s2 = (float2*)d_ws;
    float* pbase = (float*)((char*)d_ws + (size_t)NC * N * D * sizeof(float2));
    float* PLr = pbase + 0 * (N * D);
    float* PLi = pbase + 1 * (N * D);
    float* PTr = pbase + 2 * (N * D);
    float* PTi = pbase + 3 * (N * D);
    float* PCr = pbase + 4 * (N * D);
    float* PCi = pbase + 5 * (N * D);

    k_pre<<<(N * D) / 256, 256, 0, stream>>>(Delta, A_re, A_im, B_re, B_im,
                                             C_re, C_im, PLr, PLi, PTr, PTi,
                                             PCr, PCi);
    k_local<<<NC * (D / 64), 256, 0, stream>>>(x, PLr, PLi, s2);
    k_scan<<<(N * D) / 256, 256, 0, stream>>>(PTr, PTi, s2);
    k_out<<<NC * (D / 64), 256, 0, stream>>>(x, PLr, PLi, PCr, PCi, Dp, s2, out);
}